// Round 5
// baseline (602.717 us; speedup 1.0000x reference)
//
#include <hip/hip_runtime.h>

// ---------------------------------------------------------------------------
// Fused multi-head self-attention, MI355X bf16-MFMA implementation.
// B=4, S=2048, E=1024, H=16, D=64.
// Pipeline: cvt x->bf16 | pack W^T bf16 | GEMM1 (QKV proj, bias) |
//           repack V->V^T | flash-attn (swapped-QK^T, in-reg softmax) |
//           GEMM2 (out proj, bias, f32 out)
// ---------------------------------------------------------------------------

typedef __attribute__((ext_vector_type(4)))  float   f32x4;
typedef __attribute__((ext_vector_type(16))) float   f32x16;
typedef __attribute__((ext_vector_type(8)))  __bf16  bf16x8;
typedef __attribute__((ext_vector_type(4)))  __bf16  bf16x4;
typedef __attribute__((ext_vector_type(4)))  unsigned int u32x4;
typedef unsigned int u32;

__device__ __forceinline__ f32x4 fzero4() {
    f32x4 z = {0.f, 0.f, 0.f, 0.f};
    return z;
}
__device__ __forceinline__ f32x16 fzero16() {
    f32x16 z;
#pragma unroll
    for (int i = 0; i < 16; i++) z[i] = 0.f;
    return z;
}

__device__ __forceinline__ u32 cvtpk_bf16(float lo, float hi_) {
    u32 r;
    asm("v_cvt_pk_bf16_f32 %0, %1, %2" : "=v"(r) : "v"(lo), "v"(hi_));
    return r;
}

__device__ __forceinline__ void gload_lds16(const void* g, void* l) {
    __builtin_amdgcn_global_load_lds(
        (const __attribute__((address_space(1))) u32*)g,
        (__attribute__((address_space(3))) u32*)l, 16, 0, 0);
}

// ---------------------------------------------------------------------------
// fp32 -> bf16 elementwise convert (4 elems/thread, vectorized)
// ---------------------------------------------------------------------------
__global__ __launch_bounds__(256) void cvt_f32_bf16_4(
    const float* __restrict__ s, __bf16* __restrict__ d, long n) {
    long i = ((long)blockIdx.x * 256 + threadIdx.x) * 4;
    if (i >= n) return;
    float4 v = *(const float4*)(s + i);
    bf16x4 o = { (__bf16)v.x, (__bf16)v.y, (__bf16)v.z, (__bf16)v.w };
    *(bf16x4*)(d + i) = o;
}

// ---------------------------------------------------------------------------
// Batched transpose-pack: src f32 [z][R][C] -> dst bf16 [z][C][R]
// ---------------------------------------------------------------------------
__global__ __launch_bounds__(256) void pack_w_t(
    const float* __restrict__ src, __bf16* __restrict__ dst, int R, int C) {
    __shared__ float t[32][33];
    const int z = blockIdx.z;
    src += (size_t)z * R * C;
    dst += (size_t)z * R * C;
    const int r0 = blockIdx.x * 32, c0 = blockIdx.y * 32;
    const int x = threadIdx.x, y = threadIdx.y;
#pragma unroll
    for (int i = 0; i < 4; i++)
        t[y + i * 8][x] = src[(size_t)(r0 + y + i * 8) * C + c0 + x];
    __syncthreads();
#pragma unroll
    for (int i = 0; i < 4; i++)
        dst[(size_t)(c0 + y + i * 8) * R + r0 + x] = (__bf16)t[x][y + i * 8];
}

// ---------------------------------------------------------------------------
// bias pack: bqkv[t*1024 + r] = {bq,bk,bv}[r]
// ---------------------------------------------------------------------------
__global__ __launch_bounds__(256) void pack_bias(
    const float* __restrict__ bq, const float* __restrict__ bk,
    const float* __restrict__ bv, float* __restrict__ bqkv) {
    int n = blockIdx.x * 256 + threadIdx.x;
    if (n >= 3072) return;
    int t = n >> 10, r = n & 1023;
    const float* s = (t == 0) ? bq : (t == 1) ? bk : bv;
    bqkv[n] = s[r];
}

// ---------------------------------------------------------------------------
// GEMM, m97 structure: C[M][N](+bias) = A[M][K] * Bt[N][K]^T
// 128x128 tile, BK=32, 256 threads (4 waves 2x2), global_load_lds staging.
// ---------------------------------------------------------------------------
template <bool F32OUT>
__global__ __launch_bounds__(256) void gemm_bt(
    const __bf16* __restrict__ A, const __bf16* __restrict__ Bt,
    const float* __restrict__ bias, void* __restrict__ Cout,
    int M, int N, int K, int ldc) {
    __shared__ __bf16 As[128 * 32];
    __shared__ __bf16 Bs[128 * 32];
    const int tid  = threadIdx.x;
    const int lane = tid & 63, wid = tid >> 6;
    const int wr = wid >> 1, wc = wid & 1;
    const int l15 = lane & 15, l4 = lane >> 4;
    const int bn = blockIdx.x, bm = blockIdx.y;
    const long arow = (long)bm * 128 + (tid >> 2);
    const long brow = (long)bn * 128 + (tid >> 2);
    const int  kcol = (tid & 3) * 8;

    f32x4 acc[4][4];
#pragma unroll
    for (int i = 0; i < 4; i++)
#pragma unroll
        for (int j = 0; j < 4; j++) acc[i][j] = fzero4();

    for (int k0 = 0; k0 < K; k0 += 32) {
        gload_lds16(A + arow * K + k0 + kcol,        (char*)As + wid * 1024);
        gload_lds16(A + (arow + 64) * K + k0 + kcol, (char*)As + 4096 + wid * 1024);
        gload_lds16(Bt + brow * K + k0 + kcol,        (char*)Bs + wid * 1024);
        gload_lds16(Bt + (brow + 64) * K + k0 + kcol, (char*)Bs + 4096 + wid * 1024);
        __syncthreads();
        bf16x8 a[4], b[4];
#pragma unroll
        for (int mi = 0; mi < 4; mi++)
            a[mi] = *(const bf16x8*)&As[(wr * 64 + mi * 16 + l15) * 32 + l4 * 8];
#pragma unroll
        for (int ni = 0; ni < 4; ni++)
            b[ni] = *(const bf16x8*)&Bs[(wc * 64 + ni * 16 + l15) * 32 + l4 * 8];
#pragma unroll
        for (int mi = 0; mi < 4; mi++)
#pragma unroll
            for (int ni = 0; ni < 4; ni++)
                acc[mi][ni] = __builtin_amdgcn_mfma_f32_16x16x32_bf16(
                    a[mi], b[ni], acc[mi][ni], 0, 0, 0);
        __syncthreads();
    }

#pragma unroll
    for (int mi = 0; mi < 4; mi++)
#pragma unroll
        for (int ni = 0; ni < 4; ni++) {
            const int row = bm * 128 + wr * 64 + mi * 16 + l4 * 4;
            const int col = bn * 128 + wc * 64 + ni * 16 + l15;
            const float bv = bias ? bias[col] : 0.f;
#pragma unroll
            for (int r = 0; r < 4; r++) {
                float v = acc[mi][ni][r] + bv;
                if (F32OUT)
                    ((float*)Cout)[(long)(row + r) * ldc + col] = v;
                else
                    ((__bf16*)Cout)[(long)(row + r) * ldc + col] = (__bf16)v;
            }
        }
}

// ---------------------------------------------------------------------------
// V repack: QKV[(b*S+s)*3072 + 2048 + h*64 + d] -> VT[(bh*64 + d)*2048 + s]
// ---------------------------------------------------------------------------
__global__ __launch_bounds__(256) void repack_vt(
    const __bf16* __restrict__ QKV, __bf16* __restrict__ VT) {
    __shared__ __bf16 t[32][33];
    const int s0 = blockIdx.x * 32, d0 = blockIdx.y * 32, bh = blockIdx.z;
    const int b = bh >> 4, h = bh & 15;
    const int x = threadIdx.x, y = threadIdx.y;
    const __bf16* src = QKV + (size_t)(b * 2048) * 3072 + 2048 + h * 64;
#pragma unroll
    for (int i = 0; i < 4; i++)
        t[y + i * 8][x] = src[(size_t)(s0 + y + i * 8) * 3072 + d0 + x];
    __syncthreads();
    __bf16* dst = VT + (size_t)bh * 64 * 2048;
#pragma unroll
    for (int i = 0; i < 4; i++)
        dst[(size_t)(d0 + y + i * 8) * 2048 + s0 + x] = t[x][y + i * 8];
}

// ---------------------------------------------------------------------------
// Flash attention fwd, v5 (= v4 but cross-half reduce via __shfl_xor(.,32),
// the round-2-proven primitive; the tied-operand permlane reduce was the
// correctness hazard -- identical-value "+v" pairs can coalesce to one reg).
// Swapped-QK^T, in-register softmax, no main-loop LDS, XCD-chunked swizzle,
// tree reductions, setprio. Block = (b, h, 128-row Q tile); 4 waves x 32 rows.
// KV tile = 64. mfma_32x32x16 throughout.
//   S^T = mfma(A=K, B=Q):   lane q-col = lane&31 -> ONE q row per lane.
//   O^T = mfma(A=V^T, B=P^T): same lane->q mapping, scalar m/l/alpha.
// ---------------------------------------------------------------------------

#define ATTN_TILE(T0, KC, KN, PREF)                                            \
  {                                                                            \
    bf16x8 vf[8];                                                              \
    _Pragma("unroll")                                                          \
    for (int f = 0; f < 8; f++) {                                              \
      const int dc = f >> 2, kkt = f & 3;                                      \
      vf[f] = *(const bf16x8*)(Vb + (size_t)(dc * 32 + l31) * S + (T0) +       \
                               kkt * 16 + hi * 8);                             \
    }                                                                          \
    f32x16 s0 = fzero16(), s1 = fzero16();                                     \
    __builtin_amdgcn_s_setprio(1);                                             \
    _Pragma("unroll")                                                          \
    for (int kk = 0; kk < 4; kk++) {                                           \
      s0 = __builtin_amdgcn_mfma_f32_32x32x16_bf16(KC[kk],     qf[kk], s0, 0, 0, 0); \
      s1 = __builtin_amdgcn_mfma_f32_32x32x16_bf16(KC[4 + kk], qf[kk], s1, 0, 0, 0); \
    }                                                                          \
    __builtin_amdgcn_s_setprio(0);                                             \
    if (PREF) {                                                                \
      _Pragma("unroll")                                                        \
      for (int f = 0; f < 8; f++) {                                            \
        const int tc = f >> 2, kk = f & 3;                                     \
        KN[f] = *(const bf16x8*)(Kb + (size_t)((T0) + 64 + tc * 32 + l31) *    \
                                 LDQ + kk * 16 + hi * 8);                      \
      }                                                                        \
    }                                                                          \
    /* ---- row max: log-depth tree + cross-half shfl ---- */                  \
    float mm[16];                                                              \
    _Pragma("unroll")                                                          \
    for (int i = 0; i < 16; i++) mm[i] = fmaxf(s0[i], s1[i]);                  \
    _Pragma("unroll")                                                          \
    for (int st = 8; st >= 1; st >>= 1)                                        \
      _Pragma("unroll")                                                        \
      for (int i = 0; i < st; i++) mm[i] = fmaxf(mm[i], mm[i + st]);           \
    const float pm = fmaxf(mm[0], __shfl_xor(mm[0], 32));                      \
    /* ---- unconditional rescale (P stays in [0,1]) ---- */                   \
    const float mnew = fmaxf(m_r, pm);                                         \
    const float alpha = exp2f((m_r - mnew) * csc);                             \
    m_r = mnew;                                                                \
    l_r *= alpha;                                                              \
    _Pragma("unroll")                                                          \
    for (int i = 0; i < 16; i++) { o0[i] *= alpha; o1[i] *= alpha; }           \
    const float mc = m_r * csc;                                                \
    float ss[16];                                                              \
    _Pragma("unroll")                                                          \
    for (int i = 0; i < 16; i++) {                                             \
      float p0 = exp2f(s0[i] * csc - mc); s0[i] = p0;                          \
      float p1 = exp2f(s1[i] * csc - mc); s1[i] = p1;                          \
      ss[i] = p0 + p1;                                                         \
    }                                                                          \
    _Pragma("unroll")                                                          \
    for (int st = 8; st >= 1; st >>= 1)                                        \
      _Pragma("unroll")                                                        \
      for (int i = 0; i < st; i++) ss[i] += ss[i + st];                        \
    l_r += ss[0] + __shfl_xor(ss[0], 32);                                      \
    _Pragma("unroll")                                                          \
    for (int kkt = 0; kkt < 4; kkt++) {                                        \
      const int r0 = (kkt & 1) * 8;                                            \
      u32 w0, w1, w2, w3;                                                      \
      if (kkt < 2) {                                                           \
        w0 = cvtpk_bf16(s0[r0],     s0[r0 + 1]);                               \
        w1 = cvtpk_bf16(s0[r0 + 2], s0[r0 + 3]);                               \
        w2 = cvtpk_bf16(s0[r0 + 4], s0[r0 + 5]);                               \
        w3 = cvtpk_bf16(s0[r0 + 6], s0[r0 + 7]);                               \
      } else {                                                                 \
        w0 = cvtpk_bf16(s1[r0],     s1[r0 + 1]);                               \
        w1 = cvtpk_bf16(s1[r0 + 2], s1[r0 + 3]);                               \
        w2 = cvtpk_bf16(s1[r0 + 4], s1[r0 + 5]);                               \
        w3 = cvtpk_bf16(s1[r0 + 6], s1[r0 + 7]);                               \
      }                                                                        \
      asm("v_permlane32_swap_b32 %0, %1" : "+v"(w0), "+v"(w2));                \
      asm("v_permlane32_swap_b32 %0, %1" : "+v"(w1), "+v"(w3));                \
      u32x4 pw = {w0, w1, w2, w3};                                             \
      bf16x8 pf = __builtin_bit_cast(bf16x8, pw);                              \
      __builtin_amdgcn_s_setprio(1);                                           \
      o0 = __builtin_amdgcn_mfma_f32_32x32x16_bf16(vf[kkt],     pf, o0, 0, 0, 0); \
      o1 = __builtin_amdgcn_mfma_f32_32x32x16_bf16(vf[4 + kkt], pf, o1, 0, 0, 0); \
      __builtin_amdgcn_s_setprio(0);                                           \
    }                                                                          \
  }

__global__ __launch_bounds__(256, 4) void attn_fwd(
    const __bf16* __restrict__ QKV, const __bf16* __restrict__ VT,
    __bf16* __restrict__ Z) {
    const int S = 2048, LDQ = 3072;
    // XCD-chunked swizzle: grid=1024, 8 XCDs -> XCD x owns logical blocks
    // [x*128, (x+1)*128) = 8 heads' worth of q-tiles; K/V per XCD = 4MB = L2.
    const int d = blockIdx.x;
    const int blk = (d & 7) * 128 + (d >> 3);
    const int qt = blk & 15, bh = blk >> 4, b = bh >> 4, h = bh & 15;
    const int tid = threadIdx.x, wid = tid >> 6, lane = tid & 63;
    const int l31 = lane & 31, hi = lane >> 5;

    __shared__ __bf16 Tl[128][72];   // epilogue transpose only (pad 72)

    const __bf16* Qb = QKV + (size_t)b * S * LDQ + h * 64;
    const __bf16* Kb = Qb + 1024;
    const __bf16* Vb = VT + (size_t)bh * 64 * S;
    const int qrow = qt * 128 + wid * 32;

    bf16x8 qf[4];
#pragma unroll
    for (int kk = 0; kk < 4; kk++)
        qf[kk] = *(const bf16x8*)(Qb + (size_t)(qrow + l31) * LDQ + kk * 16 + hi * 8);

    f32x16 o0 = fzero16(), o1 = fzero16();
    float m_r = -1e30f, l_r = 0.f;
    const float csc = 0.18033688011f;   // log2(e) / sqrt(64)

    bf16x8 kA[8], kB[8];
#pragma unroll
    for (int f = 0; f < 8; f++) {
        const int tc = f >> 2, kk = f & 3;
        kA[f] = *(const bf16x8*)(Kb + (size_t)(tc * 32 + l31) * LDQ + kk * 16 + hi * 8);
    }

    for (int t0 = 0; t0 < S; t0 += 128) {
        ATTN_TILE(t0,      kA, kB, true)
        ATTN_TILE(t0 + 64, kB, kA, (t0 + 128 < S))
    }

    // ---- epilogue: normalize, transpose via LDS, coalesced store ----
    const float inv = 1.0f / l_r;
    const int trow = wid * 32 + l31;
#pragma unroll
    for (int g = 0; g < 4; g++) {
        bf16x4 t4a, t4b;
#pragma unroll
        for (int j = 0; j < 4; j++) {
            t4a[j] = (__bf16)(o0[4 * g + j] * inv);
            t4b[j] = (__bf16)(o1[4 * g + j] * inv);
        }
        *(bf16x4*)&Tl[trow][g * 8 + hi * 4]      = t4a;   // d = 8g+4hi+j
        *(bf16x4*)&Tl[trow][32 + g * 8 + hi * 4] = t4b;   // d = 32+8g+4hi+j
    }
    asm volatile("s_waitcnt lgkmcnt(0)" ::: "memory");
    __builtin_amdgcn_sched_barrier(0);

    const int rr = wid * 32 + (lane >> 1);
    const int ch = (lane & 1) * 32;
#pragma unroll
    for (int i = 0; i < 4; i++) {
        bf16x8 z = *(const bf16x8*)&Tl[rr][ch + i * 8];
        *(bf16x8*)&Z[((size_t)b * S + qt * 128 + rr) * 1024 + h * 64 + ch + i * 8] = z;
    }
}

// ---------------------------------------------------------------------------
// Launcher
// ---------------------------------------------------------------------------
extern "C" void kernel_launch(void* const* d_in, const int* in_sizes, int n_in,
                              void* d_out, int out_size, void* d_ws, size_t ws_size,
                              hipStream_t stream) {
    const float* x  = (const float*)d_in[0];
    const float* Wq = (const float*)d_in[1];
    const float* Wk = (const float*)d_in[2];
    const float* Wv = (const float*)d_in[3];
    const float* bq = (const float*)d_in[4];
    const float* bk = (const float*)d_in[5];
    const float* bv = (const float*)d_in[6];
    const float* Wo = (const float*)d_in[7];
    const float* bo = (const float*)d_in[8];
    float* out = (float*)d_out;

    // workspace carve-up (~109 MB)
    char* p = (char*)d_ws;
    __bf16* xb   = (__bf16*)p; p += 8192L * 1024 * 2;
    __bf16* Wqkv = (__bf16*)p; p += 3072L * 1024 * 2;
    float*  bqkv = (float*)p;  p += 3072L * 4;
    __bf16* QKV  = (__bf16*)p; p += 8192L * 3072 * 2;
    __bf16* VTb  = (__bf16*)p; p += 64L * 64 * 2048 * 2;
    __bf16* Zb   = (__bf16*)p; p += 8192L * 1024 * 2;
    __bf16* Wot  = (__bf16*)p; p += 1024L * 1024 * 2;

    cvt_f32_bf16_4<<<8192, 256, 0, stream>>>(x, xb, 8192L * 1024);
    pack_w_t<<<dim3(32, 2, 16), dim3(32, 8), 0, stream>>>(Wq, Wqkv,                1024, 64);
    pack_w_t<<<dim3(32, 2, 16), dim3(32, 8), 0, stream>>>(Wk, Wqkv + 1024L * 1024, 1024, 64);
    pack_w_t<<<dim3(32, 2, 16), dim3(32, 8), 0, stream>>>(Wv, Wqkv + 2048L * 1024, 1024, 64);
    pack_w_t<<<dim3(32, 32, 1), dim3(32, 8), 0, stream>>>(Wo, Wot, 1024, 1024);
    pack_bias<<<12, 256, 0, stream>>>(bq, bk, bv, bqkv);

    // QKV projection: [8192,1024] x [1024,3072] + bias -> bf16 [8192,3072]
    gemm_bt<false><<<dim3(24, 64), 256, 0, stream>>>(xb, Wqkv, bqkv, QKV,
                                                     8192, 3072, 1024, 3072);
    repack_vt<<<dim3(64, 2, 64), dim3(32, 8), 0, stream>>>(QKV, VTb);
    attn_fwd<<<1024, 256, 0, stream>>>(QKV, VTb, Zb);
    // out projection: [8192,1024] x [1024,1024] + bo -> f32 out
    gemm_bt<true><<<dim3(8, 64), 256, 0, stream>>>(Zb, Wot, bo, out,
                                                   8192, 1024, 1024, 1024);
}

// Round 6
// 366.112 us; speedup vs baseline: 1.6463x; 1.6463x over previous
//
#include <hip/hip_runtime.h>

// ---------------------------------------------------------------------------
// Fused multi-head self-attention, MI355X bf16-MFMA implementation.
// B=4, S=2048, E=1024, H=16, D=64.
// Pipeline: cvt x->bf16 | pack W^T bf16 | GEMM1 (QKV proj, bias) |
//           repack V->V^T | flash-attn (swapped-QK^T, in-reg softmax) |
//           GEMM2 (out proj, bias, f32 out)
// ---------------------------------------------------------------------------

typedef __attribute__((ext_vector_type(4)))  float   f32x4;
typedef __attribute__((ext_vector_type(16))) float   f32x16;
typedef __attribute__((ext_vector_type(8)))  __bf16  bf16x8;
typedef __attribute__((ext_vector_type(4)))  __bf16  bf16x4;
typedef __attribute__((ext_vector_type(4)))  unsigned int u32x4;
typedef unsigned int u32;

__device__ __forceinline__ f32x4 fzero4() {
    f32x4 z = {0.f, 0.f, 0.f, 0.f};
    return z;
}
__device__ __forceinline__ f32x16 fzero16() {
    f32x16 z;
#pragma unroll
    for (int i = 0; i < 16; i++) z[i] = 0.f;
    return z;
}

__device__ __forceinline__ u32 cvtpk_bf16(float lo, float hi_) {
    u32 r;
    asm("v_cvt_pk_bf16_f32 %0, %1, %2" : "=v"(r) : "v"(lo), "v"(hi_));
    return r;
}

__device__ __forceinline__ void gload_lds16(const void* g, void* l) {
    __builtin_amdgcn_global_load_lds(
        (const __attribute__((address_space(1))) u32*)g,
        (__attribute__((address_space(3))) u32*)l, 16, 0, 0);
}

// ---------------------------------------------------------------------------
// fp32 -> bf16 elementwise convert (4 elems/thread, vectorized)
// ---------------------------------------------------------------------------
__global__ __launch_bounds__(256) void cvt_f32_bf16_4(
    const float* __restrict__ s, __bf16* __restrict__ d, long n) {
    long i = ((long)blockIdx.x * 256 + threadIdx.x) * 4;
    if (i >= n) return;
    float4 v = *(const float4*)(s + i);
    bf16x4 o = { (__bf16)v.x, (__bf16)v.y, (__bf16)v.z, (__bf16)v.w };
    *(bf16x4*)(d + i) = o;
}

// ---------------------------------------------------------------------------
// Batched transpose-pack: src f32 [z][R][C] -> dst bf16 [z][C][R]
// ---------------------------------------------------------------------------
__global__ __launch_bounds__(256) void pack_w_t(
    const float* __restrict__ src, __bf16* __restrict__ dst, int R, int C) {
    __shared__ float t[32][33];
    const int z = blockIdx.z;
    src += (size_t)z * R * C;
    dst += (size_t)z * R * C;
    const int r0 = blockIdx.x * 32, c0 = blockIdx.y * 32;
    const int x = threadIdx.x, y = threadIdx.y;
#pragma unroll
    for (int i = 0; i < 4; i++)
        t[y + i * 8][x] = src[(size_t)(r0 + y + i * 8) * C + c0 + x];
    __syncthreads();
#pragma unroll
    for (int i = 0; i < 4; i++)
        dst[(size_t)(c0 + y + i * 8) * R + r0 + x] = (__bf16)t[x][y + i * 8];
}

// ---------------------------------------------------------------------------
// bias pack: bqkv[t*1024 + r] = {bq,bk,bv}[r]
// ---------------------------------------------------------------------------
__global__ __launch_bounds__(256) void pack_bias(
    const float* __restrict__ bq, const float* __restrict__ bk,
    const float* __restrict__ bv, float* __restrict__ bqkv) {
    int n = blockIdx.x * 256 + threadIdx.x;
    if (n >= 3072) return;
    int t = n >> 10, r = n & 1023;
    const float* s = (t == 0) ? bq : (t == 1) ? bk : bv;
    bqkv[n] = s[r];
}

// ---------------------------------------------------------------------------
// GEMM, m97 structure: C[M][N](+bias) = A[M][K] * Bt[N][K]^T
// 128x128 tile, BK=32, 256 threads (4 waves 2x2), global_load_lds staging.
// ---------------------------------------------------------------------------
template <bool F32OUT>
__global__ __launch_bounds__(256) void gemm_bt(
    const __bf16* __restrict__ A, const __bf16* __restrict__ Bt,
    const float* __restrict__ bias, void* __restrict__ Cout,
    int M, int N, int K, int ldc) {
    __shared__ __bf16 As[128 * 32];
    __shared__ __bf16 Bs[128 * 32];
    const int tid  = threadIdx.x;
    const int lane = tid & 63, wid = tid >> 6;
    const int wr = wid >> 1, wc = wid & 1;
    const int l15 = lane & 15, l4 = lane >> 4;
    const int bn = blockIdx.x, bm = blockIdx.y;
    const long arow = (long)bm * 128 + (tid >> 2);
    const long brow = (long)bn * 128 + (tid >> 2);
    const int  kcol = (tid & 3) * 8;

    f32x4 acc[4][4];
#pragma unroll
    for (int i = 0; i < 4; i++)
#pragma unroll
        for (int j = 0; j < 4; j++) acc[i][j] = fzero4();

    for (int k0 = 0; k0 < K; k0 += 32) {
        gload_lds16(A + arow * K + k0 + kcol,        (char*)As + wid * 1024);
        gload_lds16(A + (arow + 64) * K + k0 + kcol, (char*)As + 4096 + wid * 1024);
        gload_lds16(Bt + brow * K + k0 + kcol,        (char*)Bs + wid * 1024);
        gload_lds16(Bt + (brow + 64) * K + k0 + kcol, (char*)Bs + 4096 + wid * 1024);
        __syncthreads();
        bf16x8 a[4], b[4];
#pragma unroll
        for (int mi = 0; mi < 4; mi++)
            a[mi] = *(const bf16x8*)&As[(wr * 64 + mi * 16 + l15) * 32 + l4 * 8];
#pragma unroll
        for (int ni = 0; ni < 4; ni++)
            b[ni] = *(const bf16x8*)&Bs[(wc * 64 + ni * 16 + l15) * 32 + l4 * 8];
#pragma unroll
        for (int mi = 0; mi < 4; mi++)
#pragma unroll
            for (int ni = 0; ni < 4; ni++)
                acc[mi][ni] = __builtin_amdgcn_mfma_f32_16x16x32_bf16(
                    a[mi], b[ni], acc[mi][ni], 0, 0, 0);
        __syncthreads();
    }

#pragma unroll
    for (int mi = 0; mi < 4; mi++)
#pragma unroll
        for (int ni = 0; ni < 4; ni++) {
            const int row = bm * 128 + wr * 64 + mi * 16 + l4 * 4;
            const int col = bn * 128 + wc * 64 + ni * 16 + l15;
            const float bv = bias ? bias[col] : 0.f;
#pragma unroll
            for (int r = 0; r < 4; r++) {
                float v = acc[mi][ni][r] + bv;
                if (F32OUT)
                    ((float*)Cout)[(long)(row + r) * ldc + col] = v;
                else
                    ((__bf16*)Cout)[(long)(row + r) * ldc + col] = (__bf16)v;
            }
        }
}

// ---------------------------------------------------------------------------
// V repack: QKV[(b*S+s)*3072 + 2048 + h*64 + d] -> VT[(bh*64 + d)*2048 + s]
// ---------------------------------------------------------------------------
__global__ __launch_bounds__(256) void repack_vt(
    const __bf16* __restrict__ QKV, __bf16* __restrict__ VT) {
    __shared__ __bf16 t[32][33];
    const int s0 = blockIdx.x * 32, d0 = blockIdx.y * 32, bh = blockIdx.z;
    const int b = bh >> 4, h = bh & 15;
    const int x = threadIdx.x, y = threadIdx.y;
    const __bf16* src = QKV + (size_t)(b * 2048) * 3072 + 2048 + h * 64;
#pragma unroll
    for (int i = 0; i < 4; i++)
        t[y + i * 8][x] = src[(size_t)(s0 + y + i * 8) * 3072 + d0 + x];
    __syncthreads();
    __bf16* dst = VT + (size_t)bh * 64 * 2048;
#pragma unroll
    for (int i = 0; i < 4; i++)
        dst[(size_t)(d0 + y + i * 8) * 2048 + s0 + x] = t[x][y + i * 8];
}

// ---------------------------------------------------------------------------
// Flash attention fwd, v6 = round-2 config (launch_bounds(256,2), NO XCD
// swizzle -- round 5 showed (256,4) forces K-dbuf spill to scratch: VGPR 64,
// WRITE_SIZE 1.1GB) + the value-safe round-5 additions (tree reductions,
// shfl_xor(32) cross-half reduce, setprio around MFMA).
// Swapped-QK^T, in-register softmax, no main-loop LDS.
// Block = (b, h, 128-row Q tile); 4 waves x 32 q-rows. KV tile = 64.
//   S^T = mfma(A=K, B=Q):   lane q-col = lane&31 -> ONE q row per lane.
//   O^T = mfma(A=V^T, B=P^T): same lane->q mapping, scalar m/l/alpha.
// ---------------------------------------------------------------------------

#define ATTN_TILE(T0, KC, KN, PREF)                                            \
  {                                                                            \
    bf16x8 vf[8];                                                              \
    _Pragma("unroll")                                                          \
    for (int f = 0; f < 8; f++) {                                              \
      const int dc = f >> 2, kkt = f & 3;                                      \
      vf[f] = *(const bf16x8*)(Vb + (size_t)(dc * 32 + l31) * S + (T0) +       \
                               kkt * 16 + hi * 8);                             \
    }                                                                          \
    f32x16 s0 = fzero16(), s1 = fzero16();                                     \
    __builtin_amdgcn_s_setprio(1);                                             \
    _Pragma("unroll")                                                          \
    for (int kk = 0; kk < 4; kk++) {                                           \
      s0 = __builtin_amdgcn_mfma_f32_32x32x16_bf16(KC[kk],     qf[kk], s0, 0, 0, 0); \
      s1 = __builtin_amdgcn_mfma_f32_32x32x16_bf16(KC[4 + kk], qf[kk], s1, 0, 0, 0); \
    }                                                                          \
    __builtin_amdgcn_s_setprio(0);                                             \
    if (PREF) {                                                                \
      _Pragma("unroll")                                                        \
      for (int f = 0; f < 8; f++) {                                            \
        const int tc = f >> 2, kk = f & 3;                                     \
        KN[f] = *(const bf16x8*)(Kb + (size_t)((T0) + 64 + tc * 32 + l31) *    \
                                 LDQ + kk * 16 + hi * 8);                      \
      }                                                                        \
    }                                                                          \
    /* ---- row max: log-depth tree + cross-half shfl ---- */                  \
    float mm[16];                                                              \
    _Pragma("unroll")                                                          \
    for (int i = 0; i < 16; i++) mm[i] = fmaxf(s0[i], s1[i]);                  \
    _Pragma("unroll")                                                          \
    for (int st = 8; st >= 1; st >>= 1)                                        \
      _Pragma("unroll")                                                        \
      for (int i = 0; i < st; i++) mm[i] = fmaxf(mm[i], mm[i + st]);           \
    const float pm = fmaxf(mm[0], __shfl_xor(mm[0], 32));                      \
    /* ---- unconditional rescale (P stays in [0,1]) ---- */                   \
    const float mnew = fmaxf(m_r, pm);                                         \
    const float alpha = exp2f((m_r - mnew) * csc);                             \
    m_r = mnew;                                                                \
    l_r *= alpha;                                                              \
    _Pragma("unroll")                                                          \
    for (int i = 0; i < 16; i++) { o0[i] *= alpha; o1[i] *= alpha; }           \
    const float mc = m_r * csc;                                                \
    float ss[16];                                                              \
    _Pragma("unroll")                                                          \
    for (int i = 0; i < 16; i++) {                                             \
      float p0 = exp2f(s0[i] * csc - mc); s0[i] = p0;                          \
      float p1 = exp2f(s1[i] * csc - mc); s1[i] = p1;                          \
      ss[i] = p0 + p1;                                                         \
    }                                                                          \
    _Pragma("unroll")                                                          \
    for (int st = 8; st >= 1; st >>= 1)                                        \
      _Pragma("unroll")                                                        \
      for (int i = 0; i < st; i++) ss[i] += ss[i + st];                        \
    l_r += ss[0] + __shfl_xor(ss[0], 32);                                      \
    _Pragma("unroll")                                                          \
    for (int kkt = 0; kkt < 4; kkt++) {                                        \
      const int r0 = (kkt & 1) * 8;                                            \
      u32 w0, w1, w2, w3;                                                      \
      if (kkt < 2) {                                                           \
        w0 = cvtpk_bf16(s0[r0],     s0[r0 + 1]);                               \
        w1 = cvtpk_bf16(s0[r0 + 2], s0[r0 + 3]);                               \
        w2 = cvtpk_bf16(s0[r0 + 4], s0[r0 + 5]);                               \
        w3 = cvtpk_bf16(s0[r0 + 6], s0[r0 + 7]);                               \
      } else {                                                                 \
        w0 = cvtpk_bf16(s1[r0],     s1[r0 + 1]);                               \
        w1 = cvtpk_bf16(s1[r0 + 2], s1[r0 + 3]);                               \
        w2 = cvtpk_bf16(s1[r0 + 4], s1[r0 + 5]);                               \
        w3 = cvtpk_bf16(s1[r0 + 6], s1[r0 + 7]);                               \
      }                                                                        \
      asm("v_permlane32_swap_b32 %0, %1" : "+v"(w0), "+v"(w2));                \
      asm("v_permlane32_swap_b32 %0, %1" : "+v"(w1), "+v"(w3));                \
      u32x4 pw = {w0, w1, w2, w3};                                             \
      bf16x8 pf = __builtin_bit_cast(bf16x8, pw);                              \
      __builtin_amdgcn_s_setprio(1);                                           \
      o0 = __builtin_amdgcn_mfma_f32_32x32x16_bf16(vf[kkt],     pf, o0, 0, 0, 0); \
      o1 = __builtin_amdgcn_mfma_f32_32x32x16_bf16(vf[4 + kkt], pf, o1, 0, 0, 0); \
      __builtin_amdgcn_s_setprio(0);                                           \
    }                                                                          \
  }

__global__ __launch_bounds__(256, 2) void attn_fwd(
    const __bf16* __restrict__ QKV, const __bf16* __restrict__ VT,
    __bf16* __restrict__ Z) {
    const int S = 2048, LDQ = 3072;
    const int blk = blockIdx.x;
    const int qt = blk & 15, bh = blk >> 4, b = bh >> 4, h = bh & 15;
    const int tid = threadIdx.x, wid = tid >> 6, lane = tid & 63;
    const int l31 = lane & 31, hi = lane >> 5;

    __shared__ __bf16 Tl[128][72];   // epilogue transpose only (pad 72)

    const __bf16* Qb = QKV + (size_t)b * S * LDQ + h * 64;
    const __bf16* Kb = Qb + 1024;
    const __bf16* Vb = VT + (size_t)bh * 64 * S;
    const int qrow = qt * 128 + wid * 32;

    bf16x8 qf[4];
#pragma unroll
    for (int kk = 0; kk < 4; kk++)
        qf[kk] = *(const bf16x8*)(Qb + (size_t)(qrow + l31) * LDQ + kk * 16 + hi * 8);

    f32x16 o0 = fzero16(), o1 = fzero16();
    float m_r = -1e30f, l_r = 0.f;
    const float csc = 0.18033688011f;   // log2(e) / sqrt(64)

    bf16x8 kA[8], kB[8];
#pragma unroll
    for (int f = 0; f < 8; f++) {
        const int tc = f >> 2, kk = f & 3;
        kA[f] = *(const bf16x8*)(Kb + (size_t)(tc * 32 + l31) * LDQ + kk * 16 + hi * 8);
    }

    for (int t0 = 0; t0 < S; t0 += 128) {
        ATTN_TILE(t0,      kA, kB, true)
        ATTN_TILE(t0 + 64, kB, kA, (t0 + 128 < S))
    }

    // ---- epilogue: normalize, transpose via LDS, coalesced store ----
    const float inv = 1.0f / l_r;
    const int trow = wid * 32 + l31;
#pragma unroll
    for (int g = 0; g < 4; g++) {
        bf16x4 t4a, t4b;
#pragma unroll
        for (int j = 0; j < 4; j++) {
            t4a[j] = (__bf16)(o0[4 * g + j] * inv);
            t4b[j] = (__bf16)(o1[4 * g + j] * inv);
        }
        *(bf16x4*)&Tl[trow][g * 8 + hi * 4]      = t4a;   // d = 8g+4hi+j
        *(bf16x4*)&Tl[trow][32 + g * 8 + hi * 4] = t4b;   // d = 32+8g+4hi+j
    }
    asm volatile("s_waitcnt lgkmcnt(0)" ::: "memory");
    __builtin_amdgcn_sched_barrier(0);

    const int rr = wid * 32 + (lane >> 1);
    const int ch = (lane & 1) * 32;
#pragma unroll
    for (int i = 0; i < 4; i++) {
        bf16x8 z = *(const bf16x8*)&Tl[rr][ch + i * 8];
        *(bf16x8*)&Z[((size_t)b * S + qt * 128 + rr) * 1024 + h * 64 + ch + i * 8] = z;
    }
}

// ---------------------------------------------------------------------------
// Launcher
// ---------------------------------------------------------------------------
extern "C" void kernel_launch(void* const* d_in, const int* in_sizes, int n_in,
                              void* d_out, int out_size, void* d_ws, size_t ws_size,
                              hipStream_t stream) {
    const float* x  = (const float*)d_in[0];
    const float* Wq = (const float*)d_in[1];
    const float* Wk = (const float*)d_in[2];
    const float* Wv = (const float*)d_in[3];
    const float* bq = (const float*)d_in[4];
    const float* bk = (const float*)d_in[5];
    const float* bv = (const float*)d_in[6];
    const float* Wo = (const float*)d_in[7];
    const float* bo = (const float*)d_in[8];
    float* out = (float*)d_out;

    // workspace carve-up (~109 MB)
    char* p = (char*)d_ws;
    __bf16* xb   = (__bf16*)p; p += 8192L * 1024 * 2;
    __bf16* Wqkv = (__bf16*)p; p += 3072L * 1024 * 2;
    float*  bqkv = (float*)p;  p += 3072L * 4;
    __bf16* QKV  = (__bf16*)p; p += 8192L * 3072 * 2;
    __bf16* VTb  = (__bf16*)p; p += 64L * 64 * 2048 * 2;
    __bf16* Zb   = (__bf16*)p; p += 8192L * 1024 * 2;
    __bf16* Wot  = (__bf16*)p; p += 1024L * 1024 * 2;

    cvt_f32_bf16_4<<<8192, 256, 0, stream>>>(x, xb, 8192L * 1024);
    pack_w_t<<<dim3(32, 2, 16), dim3(32, 8), 0, stream>>>(Wq, Wqkv,                1024, 64);
    pack_w_t<<<dim3(32, 2, 16), dim3(32, 8), 0, stream>>>(Wk, Wqkv + 1024L * 1024, 1024, 64);
    pack_w_t<<<dim3(32, 2, 16), dim3(32, 8), 0, stream>>>(Wv, Wqkv + 2048L * 1024, 1024, 64);
    pack_w_t<<<dim3(32, 32, 1), dim3(32, 8), 0, stream>>>(Wo, Wot, 1024, 1024);
    pack_bias<<<12, 256, 0, stream>>>(bq, bk, bv, bqkv);

    // QKV projection: [8192,1024] x [1024,3072] + bias -> bf16 [8192,3072]
    gemm_bt<false><<<dim3(24, 64), 256, 0, stream>>>(xb, Wqkv, bqkv, QKV,
                                                     8192, 3072, 1024, 3072);
    repack_vt<<<dim3(64, 2, 64), dim3(32, 8), 0, stream>>>(QKV, VTb);
    attn_fwd<<<1024, 256, 0, stream>>>(QKV, VTb, Zb);
    // out projection: [8192,1024] x [1024,1024] + bo -> f32 out
    gemm_bt<true><<<dim3(8, 64), 256, 0, stream>>>(Zb, Wot, bo, out,
                                                   8192, 1024, 1024, 1024);
}